// Round 1
// baseline (69.022 us; speedup 1.0000x reference)
//
#include <hip/hip_runtime.h>
#include <math.h>

namespace {
constexpr int kN = 1024;   // variable nodes
constexpr int kE = 3072;   // edges
constexpr int kB = 128;    // batch
constexpr float kClip = 0.999999f;
}

// One wave per edge-row of vn2cn_mask [E,E]; finds the 5 partner-edge indices
// (same check node, excluding self) in deterministic (ascending) order.
__global__ __launch_bounds__(256) void extract_partners_kernel(
    const float* __restrict__ mask, int* __restrict__ part) {
  int wid = (blockIdx.x * 256 + threadIdx.x) >> 6;   // row = edge index
  int lane = threadIdx.x & 63;
  if (wid >= kE) return;
  const float* row = mask + (size_t)wid * kE;
  int cnt = 0;
  for (int j = 0; j < kE; j += 64) {
    float v = row[j + lane];
    unsigned long long m = __ballot(v != 0.0f);
    if (v != 0.0f) {
      int pos = cnt + __popcll(m & ((1ULL << lane) - 1ULL));
      if (pos < 5) part[wid * 8 + pos] = j + lane;   // padded stride 8
    }
    cnt += __popcll(m);
  }
}

// One block per batch item; whole BP state lives in LDS.
__global__ __launch_bounds__(256) void bp_kernel(
    const float* __restrict__ x, const int* __restrict__ part,
    float* __restrict__ out) {
  __shared__ float llr[kN];
  __shared__ float tmp[kE];   // VN->CN messages (tanh domain); first 1024 = tanh(0.5*x)
  __shared__ float msg[kE];   // CN->VN messages (LLR domain)
  const int b = blockIdx.x;
  const int tid = threadIdx.x;
  const float* xb = x + (size_t)b * kN;

  for (int v = tid; v < kN; v += 256) {
    float l = xb[v];
    llr[v] = l;
    tmp[v] = tanhf(0.5f * l);
  }
  __syncthreads();

  // fc0: first CN layer — product over DISTINCT partner variable nodes
  // (first_mask = clip(vn2cn @ onehot, 0, 1) dedups repeated VNs).
  for (int e = tid; e < kE; e += 256) {
    const int* pp = part + e * 8;
    int p0 = pp[0], p1 = pp[1], p2 = pp[2], p3 = pp[3], p4 = pp[4];
    int q0 = p0 / 3, q1 = p1 / 3, q2 = p2 / 3, q3 = p3 / 3, q4 = p4 / 3;
    float prod = tmp[q0];
    if (q1 != q0) prod *= tmp[q1];
    if (q2 != q0 && q2 != q1) prod *= tmp[q2];
    if (q3 != q0 && q3 != q1 && q3 != q2) prod *= tmp[q3];
    if (q4 != q0 && q4 != q1 && q4 != q2 && q4 != q3) prod *= tmp[q4];
    float y = fminf(fmaxf(prod, -kClip), kClip);
    msg[e] = 2.0f * atanhf(y);
  }
  __syncthreads();

  // out1 -> tuple slot 4 (return order is out5,out4,out3,out2,out1)
  {
    float* o = out + (size_t)4 * kB * kN + (size_t)b * kN;
    for (int v = tid; v < kN; v += 256) {
      float s = llr[v] + msg[3 * v] + msg[3 * v + 1] + msg[3 * v + 2];
      o[v] = 1.0f / (1.0f + expf(-s));
    }
  }

  for (int it = 2; it <= 5; ++it) {
    // VN update: edge e of VN v gets llr[v] + the other two CN->VN messages.
    // (reads msg/llr, writes tmp — tmp's prior readers synced after CN phase)
    for (int e = tid; e < kE; e += 256) {
      int v = e / 3;
      int base = 3 * v;
      int i = e - base;
      float s = llr[v] + msg[base + ((i + 1) % 3)] + msg[base + ((i + 2) % 3)];
      tmp[e] = tanhf(0.5f * s);
    }
    __syncthreads();
    // CN update: product over the 5 partner edges (per-edge mask, no dedup).
    for (int e = tid; e < kE; e += 256) {
      const int* pp = part + e * 8;
      float prod = tmp[pp[0]] * tmp[pp[1]] * tmp[pp[2]] * tmp[pp[3]] * tmp[pp[4]];
      float y = fminf(fmaxf(prod, -kClip), kClip);
      msg[e] = 2.0f * atanhf(y);
    }
    __syncthreads();
    // out_it -> tuple slot (5 - it)
    float* o = out + (size_t)(5 - it) * kB * kN + (size_t)b * kN;
    for (int v = tid; v < kN; v += 256) {
      float s = llr[v] + msg[3 * v] + msg[3 * v + 1] + msg[3 * v + 2];
      o[v] = 1.0f / (1.0f + expf(-s));
    }
  }
}

extern "C" void kernel_launch(void* const* d_in, const int* in_sizes, int n_in,
                              void* d_out, int out_size, void* d_ws, size_t ws_size,
                              hipStream_t stream) {
  const float* x = (const float*)d_in[0];       // [128,1024] channel LLRs
  const float* vn2cn = (const float*)d_in[3];   // [3072,3072] same-check mask
  int* part = (int*)d_ws;                        // [3072][8] partner table (uses 98 KB)
  float* out = (float*)d_out;                    // [5,128,1024] f32

  hipLaunchKernelGGL(extract_partners_kernel, dim3((kE * 64) / 256), dim3(256),
                     0, stream, vn2cn, part);
  hipLaunchKernelGGL(bp_kernel, dim3(kB), dim3(256), 0, stream, x, part, out);
}

// Round 3
// 20.235 us; speedup vs baseline: 3.4110x; 3.4110x over previous
//
#include <hip/hip_runtime.h>
#include <math.h>

namespace {
constexpr int kN = 1024;   // variable nodes
constexpr int kE = 3072;   // edges
constexpr int kB = 128;    // batch
constexpr float kClip = 0.999999f;
}

#define RCP(x) __builtin_amdgcn_rcpf(x)

// One wave per edge-row of vn2cn_mask [E,E]; finds the 5 partner-edge indices
// (same check node, excl self) in ascending order and packs them 5x12-bit
// into one uint64 per edge.
__global__ __launch_bounds__(256) void extract_partners_kernel(
    const uint4* __restrict__ mask, unsigned long long* __restrict__ part) {
  __shared__ int slots[4][8];
  const int wave = threadIdx.x >> 6, lane = threadIdx.x & 63;
  const int row = blockIdx.x * 4 + wave;
  const uint4* rp = mask + (size_t)row * (kE / 4);

  uint4 vals[12];
#pragma unroll
  for (int it = 0; it < 12; ++it) vals[it] = rp[it * 64 + lane];

  const unsigned long long lt = (1ULL << lane) - 1ULL;
  int cnt = 0;
#pragma unroll
  for (int it = 0; it < 12; ++it) {
    uint4 v = vals[it];
    unsigned long long m0 = __ballot(v.x != 0u);
    unsigned long long m1 = __ballot(v.y != 0u);
    unsigned long long m2 = __ballot(v.z != 0u);
    unsigned long long m3 = __ballot(v.w != 0u);
    int before = cnt + __popcll(m0 & lt) + __popcll(m1 & lt) +
                 __popcll(m2 & lt) + __popcll(m3 & lt);
    // uint4 element (it*64+lane) holds float columns 4*(it*64+lane) .. +3
    int idx = it * 256 + lane * 4;
    int own = 0;
    if (v.x != 0u) slots[wave][min(before + own, 7)] = idx + 0;
    own += (int)((m0 >> lane) & 1ULL);
    if (v.y != 0u) slots[wave][min(before + own, 7)] = idx + 1;
    own += (int)((m1 >> lane) & 1ULL);
    if (v.z != 0u) slots[wave][min(before + own, 7)] = idx + 2;
    own += (int)((m2 >> lane) & 1ULL);
    if (v.w != 0u) slots[wave][min(before + own, 7)] = idx + 3;
    cnt += __popcll(m0) + __popcll(m1) + __popcll(m2) + __popcll(m3);
  }
  __syncthreads();
  if (lane == 0) {
    unsigned long long pk = 0;
#pragma unroll
    for (int i = 0; i < 5; ++i)
      pk |= (unsigned long long)(slots[wave][i] & 0xFFF) << (12 * i);
    part[row] = pk;
  }
}

// One block (1024 threads) per batch item. Rational-domain BP:
//   r = e^msg = (1+y)/(1-y);  tanh(0.5*(llr+Σmsg)) = (p-1)/(p+1), p = e^llr·Πr
//   sigmoid(llr+Σmsg) = P/(1+P), P = e^llr·r0·r1·r2
// Only transcendental: one __expf per VN at init.
__global__ __launch_bounds__(1024) void bp_kernel(
    const float* __restrict__ x, const unsigned long long* __restrict__ part,
    float* __restrict__ out) {
  __shared__ float tm[kE];   // tanh-domain VN->CN messages (first kN = init per-VN)
  __shared__ float rm[kE];   // ratio-domain CN->VN messages
  const int b = blockIdx.x;
  const int tid = threadIdx.x;

  const float l = x[(size_t)b * kN + tid];
  const float E = __expf(l);
  tm[tid] = (E - 1.0f) * RCP(E + 1.0f);
  __syncthreads();

  // fc0: CN update over DISTINCT partner VNs (first_mask dedups repeated VNs)
#pragma unroll
  for (int i = 0; i < 3; ++i) {
    const int e = tid + i * 1024;
    const unsigned long long pk = part[e];
    const int p0 = (int)(pk & 0xFFF), p1 = (int)((pk >> 12) & 0xFFF),
              p2 = (int)((pk >> 24) & 0xFFF), p3 = (int)((pk >> 36) & 0xFFF),
              p4 = (int)((pk >> 48) & 0xFFF);
    const int q0 = p0 / 3, q1 = p1 / 3, q2 = p2 / 3, q3 = p3 / 3, q4 = p4 / 3;
    float prod = tm[q0];
    float f1 = tm[q1], f2 = tm[q2], f3 = tm[q3], f4 = tm[q4];
    prod *= (q1 == q0) ? 1.0f : f1;
    prod *= (q2 == q0 || q2 == q1) ? 1.0f : f2;
    prod *= (q3 == q0 || q3 == q1 || q3 == q2) ? 1.0f : f3;
    prod *= (q4 == q0 || q4 == q1 || q4 == q2 || q4 == q3) ? 1.0f : f4;
    const float y = fminf(fmaxf(prod, -kClip), kClip);
    rm[e] = (1.0f + y) * RCP(1.0f - y);
  }
  __syncthreads();

  float* ob = out + (size_t)b * kN + tid;
#pragma unroll
  for (int k = 1; k <= 4; ++k) {
    // OUT(k) (tuple slot 5-k) fused with VN update for next CN layer
    const float r0 = rm[3 * tid], r1 = rm[3 * tid + 1], r2 = rm[3 * tid + 2];
    const float P = E * r0 * r1 * r2;
    ob[(size_t)(5 - k) * kB * kN] = P * RCP(1.0f + P);
    const float p0 = E * r1 * r2, p1 = E * r0 * r2, p2 = E * r0 * r1;
    tm[3 * tid]     = (p0 - 1.0f) * RCP(p0 + 1.0f);
    tm[3 * tid + 1] = (p1 - 1.0f) * RCP(p1 + 1.0f);
    tm[3 * tid + 2] = (p2 - 1.0f) * RCP(p2 + 1.0f);
    __syncthreads();
    // CN update: product over the 5 partner edges
#pragma unroll
    for (int i = 0; i < 3; ++i) {
      const int e = tid + i * 1024;
      const unsigned long long pk = part[e];
      const float y0 = tm[pk & 0xFFF] * tm[(pk >> 12) & 0xFFF] *
                       tm[(pk >> 24) & 0xFFF] * tm[(pk >> 36) & 0xFFF] *
                       tm[(pk >> 48) & 0xFFF];
      const float y = fminf(fmaxf(y0, -kClip), kClip);
      rm[e] = (1.0f + y) * RCP(1.0f - y);
    }
    __syncthreads();
  }
  // OUT(5) -> tuple slot 0
  const float r0 = rm[3 * tid], r1 = rm[3 * tid + 1], r2 = rm[3 * tid + 2];
  const float P = E * r0 * r1 * r2;
  ob[0] = P * RCP(1.0f + P);
}

extern "C" void kernel_launch(void* const* d_in, const int* in_sizes, int n_in,
                              void* d_out, int out_size, void* d_ws, size_t ws_size,
                              hipStream_t stream) {
  const float* x = (const float*)d_in[0];       // [128,1024] channel LLRs
  const float* vn2cn = (const float*)d_in[3];   // [3072,3072] same-check mask
  unsigned long long* part = (unsigned long long*)d_ws;  // [3072] packed partners
  float* out = (float*)d_out;                    // [5,128,1024] f32

  hipLaunchKernelGGL(extract_partners_kernel, dim3(kE / 4), dim3(256), 0, stream,
                     (const uint4*)vn2cn, part);
  hipLaunchKernelGGL(bp_kernel, dim3(kB), dim3(1024), 0, stream, x, part, out);
}

// Round 4
// 18.896 us; speedup vs baseline: 3.6528x; 1.0709x over previous
//
#include <hip/hip_runtime.h>
#include <math.h>

namespace {
constexpr int kN = 1024;   // variable nodes
constexpr int kE = 3072;   // edges
constexpr int kB = 128;    // batch
constexpr float kClip = 0.999999f;
}

#define RCP(x) __builtin_amdgcn_rcpf(x)

// One wave per edge-row of vn2cn_mask [E,E], scanning only columns > row
// (upper triangle). The minimum edge of each 6-edge check group sees all 5
// partners above the diagonal (wave-uniform count == 5); it then writes the
// packed 5x12-bit partner list for ALL SIX group members. Each part[] entry
// is written exactly once. Halves mask bytes read vs a full scan.
__global__ __launch_bounds__(256) void extract_partners_kernel(
    const uint4* __restrict__ mask, unsigned long long* __restrict__ part) {
  __shared__ int slots[4][8];
  const int wave = threadIdx.x >> 6, lane = threadIdx.x & 63;
  const int row = blockIdx.x * 4 + wave;
  const uint4* rp = mask + (size_t)row * (kE / 4);
  const int it0 = (row + 1) >> 8;   // first 256-col chunk intersecting (row, E)

  // Prefetch (predicated, unrolled -> all loads outstanding together).
  uint4 vals[12];
#pragma unroll
  for (int it = 0; it < 12; ++it)
    if (it >= it0) vals[it] = rp[it * 64 + lane];

  const unsigned long long lt = (1ULL << lane) - 1ULL;
  int cnt = 0;
#pragma unroll
  for (int it = 0; it < 12; ++it) {
    if (it < it0) continue;
    uint4 v = vals[it];
    const int idx = it * 256 + lane * 4;  // float column of v.x
    const bool b0 = (v.x != 0u) & (idx + 0 > row);
    const bool b1 = (v.y != 0u) & (idx + 1 > row);
    const bool b2 = (v.z != 0u) & (idx + 2 > row);
    const bool b3 = (v.w != 0u) & (idx + 3 > row);
    unsigned long long m0 = __ballot(b0);
    unsigned long long m1 = __ballot(b1);
    unsigned long long m2 = __ballot(b2);
    unsigned long long m3 = __ballot(b3);
    int before = cnt + __popcll(m0 & lt) + __popcll(m1 & lt) +
                 __popcll(m2 & lt) + __popcll(m3 & lt);
    int own = 0;
    if (b0) slots[wave][min(before + own, 7)] = idx + 0;
    own += (int)((m0 >> lane) & 1ULL);
    if (b1) slots[wave][min(before + own, 7)] = idx + 1;
    own += (int)((m1 >> lane) & 1ULL);
    if (b2) slots[wave][min(before + own, 7)] = idx + 2;
    own += (int)((m2 >> lane) & 1ULL);
    if (b3) slots[wave][min(before + own, 7)] = idx + 3;
    cnt += __popcll(m0) + __popcll(m1) + __popcll(m2) + __popcll(m3);
  }
  __syncthreads();
  // cnt is wave-uniform; ==5 iff this row is its check group's minimum edge.
  if (cnt == 5 && lane < 6) {
    int g[6];
    g[0] = row;
#pragma unroll
    for (int i = 0; i < 5; ++i) g[i + 1] = slots[wave][i];  // ascending
    unsigned long long pk = 0;
    int sh = 0;
#pragma unroll
    for (int i = 0; i < 6; ++i)
      if (i != lane) {
        pk |= (unsigned long long)(g[i] & 0xFFF) << sh;
        sh += 12;
      }
    part[g[lane]] = pk;
  }
}

// One block (1024 threads) per batch item. Rational-domain BP:
//   r = e^msg = (1+y)/(1-y);  tanh(0.5*(llr+Σmsg)) = (p-1)/(p+1), p = e^llr·Πr
//   sigmoid(llr+Σmsg) = P/(1+P), P = e^llr·r0·r1·r2
// Only transcendental: one __expf per VN at init.
__global__ __launch_bounds__(1024) void bp_kernel(
    const float* __restrict__ x, const unsigned long long* __restrict__ part,
    float* __restrict__ out) {
  __shared__ float tm[kE];   // tanh-domain VN->CN messages (first kN = init per-VN)
  __shared__ float rm[kE];   // ratio-domain CN->VN messages
  const int b = blockIdx.x;
  const int tid = threadIdx.x;

  // Hoist the 3 packed partner words -> 15 partner indices into registers.
  const unsigned long long pk0 = part[tid];
  const unsigned long long pk1 = part[tid + 1024];
  const unsigned long long pk2 = part[tid + 2048];
  const int i00 = (int)(pk0 & 0xFFF), i01 = (int)((pk0 >> 12) & 0xFFF),
            i02 = (int)((pk0 >> 24) & 0xFFF), i03 = (int)((pk0 >> 36) & 0xFFF),
            i04 = (int)((pk0 >> 48) & 0xFFF);
  const int i10 = (int)(pk1 & 0xFFF), i11 = (int)((pk1 >> 12) & 0xFFF),
            i12 = (int)((pk1 >> 24) & 0xFFF), i13 = (int)((pk1 >> 36) & 0xFFF),
            i14 = (int)((pk1 >> 48) & 0xFFF);
  const int i20 = (int)(pk2 & 0xFFF), i21 = (int)((pk2 >> 12) & 0xFFF),
            i22 = (int)((pk2 >> 24) & 0xFFF), i23 = (int)((pk2 >> 36) & 0xFFF),
            i24 = (int)((pk2 >> 48) & 0xFFF);

  const float l = x[(size_t)b * kN + tid];
  const float E = __expf(l);
  tm[tid] = (E - 1.0f) * RCP(E + 1.0f);
  __syncthreads();

  // fc0: CN update over DISTINCT partner VNs (first_mask dedups repeated VNs)
  {
    const int ii[3][5] = {{i00, i01, i02, i03, i04},
                          {i10, i11, i12, i13, i14},
                          {i20, i21, i22, i23, i24}};
#pragma unroll
    for (int i = 0; i < 3; ++i) {
      const int q0 = ii[i][0] / 3, q1 = ii[i][1] / 3, q2 = ii[i][2] / 3,
                q3 = ii[i][3] / 3, q4 = ii[i][4] / 3;
      float prod = tm[q0];
      float f1 = tm[q1], f2 = tm[q2], f3 = tm[q3], f4 = tm[q4];
      prod *= (q1 == q0) ? 1.0f : f1;
      prod *= (q2 == q0 || q2 == q1) ? 1.0f : f2;
      prod *= (q3 == q0 || q3 == q1 || q3 == q2) ? 1.0f : f3;
      prod *= (q4 == q0 || q4 == q1 || q4 == q2 || q4 == q3) ? 1.0f : f4;
      const float y = fminf(fmaxf(prod, -kClip), kClip);
      rm[tid + i * 1024] = (1.0f + y) * RCP(1.0f - y);
    }
  }
  __syncthreads();

  float* ob = out + (size_t)b * kN + tid;
#pragma unroll
  for (int k = 1; k <= 4; ++k) {
    // OUT(k) (tuple slot 5-k) fused with VN update for next CN layer
    const float r0 = rm[3 * tid], r1 = rm[3 * tid + 1], r2 = rm[3 * tid + 2];
    const float P = E * r0 * r1 * r2;
    ob[(size_t)(5 - k) * kB * kN] = P * RCP(1.0f + P);
    const float p0 = E * r1 * r2, p1 = E * r0 * r2, p2 = E * r0 * r1;
    tm[3 * tid]     = (p0 - 1.0f) * RCP(p0 + 1.0f);
    tm[3 * tid + 1] = (p1 - 1.0f) * RCP(p1 + 1.0f);
    tm[3 * tid + 2] = (p2 - 1.0f) * RCP(p2 + 1.0f);
    __syncthreads();
    // CN update: product over the 5 partner edges
    {
      float y0 = tm[i00] * tm[i01] * tm[i02] * tm[i03] * tm[i04];
      float y = fminf(fmaxf(y0, -kClip), kClip);
      rm[tid] = (1.0f + y) * RCP(1.0f - y);
      y0 = tm[i10] * tm[i11] * tm[i12] * tm[i13] * tm[i14];
      y = fminf(fmaxf(y0, -kClip), kClip);
      rm[tid + 1024] = (1.0f + y) * RCP(1.0f - y);
      y0 = tm[i20] * tm[i21] * tm[i22] * tm[i23] * tm[i24];
      y = fminf(fmaxf(y0, -kClip), kClip);
      rm[tid + 2048] = (1.0f + y) * RCP(1.0f - y);
    }
    __syncthreads();
  }
  // OUT(5) -> tuple slot 0
  const float r0 = rm[3 * tid], r1 = rm[3 * tid + 1], r2 = rm[3 * tid + 2];
  const float P = E * r0 * r1 * r2;
  ob[0] = P * RCP(1.0f + P);
}

extern "C" void kernel_launch(void* const* d_in, const int* in_sizes, int n_in,
                              void* d_out, int out_size, void* d_ws, size_t ws_size,
                              hipStream_t stream) {
  const float* x = (const float*)d_in[0];       // [128,1024] channel LLRs
  const float* vn2cn = (const float*)d_in[3];   // [3072,3072] same-check mask
  unsigned long long* part = (unsigned long long*)d_ws;  // [3072] packed partners
  float* out = (float*)d_out;                    // [5,128,1024] f32

  hipLaunchKernelGGL(extract_partners_kernel, dim3(kE / 4), dim3(256), 0, stream,
                     (const uint4*)vn2cn, part);
  hipLaunchKernelGGL(bp_kernel, dim3(kB), dim3(1024), 0, stream, x, part, out);
}

// Round 5
// 17.983 us; speedup vs baseline: 3.8383x; 1.0508x over previous
//
#include <hip/hip_runtime.h>
#include <math.h>

namespace {
constexpr int kN = 1024;   // variable nodes
constexpr int kE = 3072;   // edges
constexpr int kB = 128;    // batch
constexpr float kClip = 0.999999f;
}

#define RCP(x) __builtin_amdgcn_rcpf(x)

// One wave per edge-row of vn2cn_mask [E,E], scanning only columns > row
// (upper triangle). The minimum edge of each 6-edge check group sees all 5
// partners above the diagonal (wave-uniform count == 5); it then writes the
// packed 5x12-bit partner list for ALL SIX group members. Each part[] entry
// is written exactly once. Halves mask bytes read vs a full scan.
__global__ __launch_bounds__(256) void extract_partners_kernel(
    const uint4* __restrict__ mask, unsigned long long* __restrict__ part) {
  __shared__ int slots[4][8];
  const int wave = threadIdx.x >> 6, lane = threadIdx.x & 63;
  const int row = blockIdx.x * 4 + wave;
  const uint4* rp = mask + (size_t)row * (kE / 4);
  const int it0 = (row + 1) >> 8;   // first 256-col chunk intersecting (row, E)

  // Prefetch (predicated, unrolled -> all loads outstanding together).
  uint4 vals[12];
#pragma unroll
  for (int it = 0; it < 12; ++it)
    if (it >= it0) vals[it] = rp[it * 64 + lane];

  const unsigned long long lt = (1ULL << lane) - 1ULL;
  int cnt = 0;
#pragma unroll
  for (int it = 0; it < 12; ++it) {
    if (it < it0) continue;
    uint4 v = vals[it];
    const int idx = it * 256 + lane * 4;  // float column of v.x
    const bool b0 = (v.x != 0u) & (idx + 0 > row);
    const bool b1 = (v.y != 0u) & (idx + 1 > row);
    const bool b2 = (v.z != 0u) & (idx + 2 > row);
    const bool b3 = (v.w != 0u) & (idx + 3 > row);
    unsigned long long m0 = __ballot(b0);
    unsigned long long m1 = __ballot(b1);
    unsigned long long m2 = __ballot(b2);
    unsigned long long m3 = __ballot(b3);
    int before = cnt + __popcll(m0 & lt) + __popcll(m1 & lt) +
                 __popcll(m2 & lt) + __popcll(m3 & lt);
    int own = 0;
    if (b0) slots[wave][min(before + own, 7)] = idx + 0;
    own += (int)((m0 >> lane) & 1ULL);
    if (b1) slots[wave][min(before + own, 7)] = idx + 1;
    own += (int)((m1 >> lane) & 1ULL);
    if (b2) slots[wave][min(before + own, 7)] = idx + 2;
    own += (int)((m2 >> lane) & 1ULL);
    if (b3) slots[wave][min(before + own, 7)] = idx + 3;
    cnt += __popcll(m0) + __popcll(m1) + __popcll(m2) + __popcll(m3);
  }
  __syncthreads();
  // cnt is wave-uniform; ==5 iff this row is its check group's minimum edge.
  if (cnt == 5 && lane < 6) {
    int g[6];
    g[0] = row;
#pragma unroll
    for (int i = 0; i < 5; ++i) g[i + 1] = slots[wave][i];  // ascending
    unsigned long long pk = 0;
    int sh = 0;
#pragma unroll
    for (int i = 0; i < 6; ++i)
      if (i != lane) {
        pk |= (unsigned long long)(g[i] & 0xFFF) << sh;
        sh += 12;
      }
    part[g[lane]] = pk;
  }
}

// One block (1024 threads) per batch item. Thread tid owns edges 3tid+{0,1,2}
// (exactly the edges of VN tid), so CN outputs y0..y2 stay in registers and
// only the tanh-domain edge messages tmE round-trip through LDS
// (double-buffered -> ONE barrier per iteration).
// y-domain algebra (y = clipped tanh message):
//   VN edge update: tanh(0.5(llr+m_a+m_b)) = (n-d)/(n+d),
//     n = e^llr (1+y_a)(1+y_b), d = (1-y_a)(1-y_b)
//   output: sigmoid(llr+m0+m1+m2) = N/(N+D),
//     N = e^llr (1+y0)(1+y1)(1+y2), D = (1-y0)(1-y1)(1-y2)
// Only transcendental: one __expf per VN at init. CN phase has zero rcp.
__global__ __launch_bounds__(1024) void bp_kernel(
    const float* __restrict__ x, const unsigned long long* __restrict__ part,
    float* __restrict__ out) {
  __shared__ float tmV[kN];      // first-layer per-VN tanh values
  __shared__ float tmE[2][kE];   // edge messages, double-buffered
  const int b = blockIdx.x;
  const int tid = threadIdx.x;

  // Partner-edge indices for the 3 owned edges -> registers (all static idx).
  int idx[3][5];
#pragma unroll
  for (int i = 0; i < 3; ++i) {
    const unsigned long long pk = part[3 * tid + i];
#pragma unroll
    for (int j = 0; j < 5; ++j) idx[i][j] = (int)((pk >> (12 * j)) & 0xFFF);
  }

  const float l = x[(size_t)b * kN + tid];
  const float E = __expf(l);
  tmV[tid] = (E - 1.0f) * RCP(E + 1.0f);
  __syncthreads();                                   // barrier 1

  float y[3];
  // fc0: CN product over DISTINCT partner VNs (first_mask dedups repeats)
#pragma unroll
  for (int i = 0; i < 3; ++i) {
    const int q0 = idx[i][0] / 3, q1 = idx[i][1] / 3, q2 = idx[i][2] / 3,
              q3 = idx[i][3] / 3, q4 = idx[i][4] / 3;
    float prod = tmV[q0];
    const float f1 = tmV[q1], f2 = tmV[q2], f3 = tmV[q3], f4 = tmV[q4];
    prod *= (q1 == q0) ? 1.0f : f1;
    prod *= (q2 == q0 || q2 == q1) ? 1.0f : f2;
    prod *= (q3 == q0 || q3 == q1 || q3 == q2) ? 1.0f : f3;
    prod *= (q4 == q0 || q4 == q1 || q4 == q2 || q4 == q3) ? 1.0f : f4;
    y[i] = fminf(fmaxf(prod, -kClip), kClip);
  }

  float* ob = out + (size_t)b * kN + tid;

  // OUT(slot) + VN update of the 3 owned edges into wbuf.
#define OUT_VN(slot, wbuf)                                                 \
  {                                                                        \
    const float a0 = 1.0f + y[0], a1 = 1.0f + y[1], a2 = 1.0f + y[2];      \
    const float s0 = 1.0f - y[0], s1 = 1.0f - y[1], s2 = 1.0f - y[2];      \
    const float Nn = E * a0 * a1 * a2;                                     \
    const float Dd = s0 * s1 * s2;                                         \
    ob[(size_t)(slot) * kB * kN] = Nn * RCP(Nn + Dd);                      \
    const float n0 = E * a1 * a2, d0 = s1 * s2;                            \
    const float n1 = E * a0 * a2, d1 = s0 * s2;                            \
    const float n2 = E * a0 * a1, d2 = s0 * s1;                            \
    (wbuf)[3 * tid + 0] = (n0 - d0) * RCP(n0 + d0);                        \
    (wbuf)[3 * tid + 1] = (n1 - d1) * RCP(n1 + d1);                        \
    (wbuf)[3 * tid + 2] = (n2 - d2) * RCP(n2 + d2);                        \
  }

  // CN product over the 5 partner edges from rbuf.
#define CN(rbuf)                                                           \
  {                                                                        \
    _Pragma("unroll") for (int i = 0; i < 3; ++i) {                        \
      const float p = (rbuf)[idx[i][0]] * (rbuf)[idx[i][1]] *              \
                      (rbuf)[idx[i][2]] * (rbuf)[idx[i][3]] *              \
                      (rbuf)[idx[i][4]];                                   \
      y[i] = fminf(fmaxf(p, -kClip), kClip);                               \
    }                                                                      \
  }

  OUT_VN(4, tmE[0]);   // out1
  __syncthreads();     // barrier 2
  CN(tmE[0]);
  OUT_VN(3, tmE[1]);   // out2
  __syncthreads();     // barrier 3
  CN(tmE[1]);
  OUT_VN(2, tmE[0]);   // out3
  __syncthreads();     // barrier 4
  CN(tmE[0]);
  OUT_VN(1, tmE[1]);   // out4
  __syncthreads();     // barrier 5
  CN(tmE[1]);
  // out5 -> slot 0 (no further VN update needed)
  {
    const float a0 = 1.0f + y[0], a1 = 1.0f + y[1], a2 = 1.0f + y[2];
    const float s0 = 1.0f - y[0], s1 = 1.0f - y[1], s2 = 1.0f - y[2];
    const float Nn = E * a0 * a1 * a2;
    const float Dd = s0 * s1 * s2;
    ob[0] = Nn * RCP(Nn + Dd);
  }
#undef OUT_VN
#undef CN
}

extern "C" void kernel_launch(void* const* d_in, const int* in_sizes, int n_in,
                              void* d_out, int out_size, void* d_ws, size_t ws_size,
                              hipStream_t stream) {
  const float* x = (const float*)d_in[0];       // [128,1024] channel LLRs
  const float* vn2cn = (const float*)d_in[3];   // [3072,3072] same-check mask
  unsigned long long* part = (unsigned long long*)d_ws;  // [3072] packed partners
  float* out = (float*)d_out;                    // [5,128,1024] f32

  hipLaunchKernelGGL(extract_partners_kernel, dim3(kE / 4), dim3(256), 0, stream,
                     (const uint4*)vn2cn, part);
  hipLaunchKernelGGL(bp_kernel, dim3(kB), dim3(1024), 0, stream, x, part, out);
}